// Round 5
// baseline (143.298 us; speedup 1.0000x reference)
//
#include <hip/hip_runtime.h>
#include <math.h>

#define S_LEN  4096
#define NCH    64
#define RPT    16          // s-rows per thread (one wave = one 16-row strip)
#define TY     4           // waves per block -> 256 threads
#define WLEN   77          // window rows per strip (61 + RPT)
#define PRE    20          // preload depth -> 5-tap prefetch distance

// 106 fused filter taps, computed on HOST (fp64, bit-matching numpy's index
// math — validated rounds 1-4, absmax 1.56e-2 vs 1.03e-1 threshold), passed
// BY VALUE -> kernarg -> scalar s_load in kernel.
struct WtArgs { float w6[62]; float w3[32]; float w1[12]; };

// ---------------------------------------------------------------------------
// Round-4 post-mortem: LDS+barrier version sat at ~58 µs, 2.4x the 24 µs HBM
// floor. Pipe budgets (VALU 11 µs, LDS 7 µs, HBM 24 µs) say the loss is
// phase lock-step: stage -> barrier -> compute -> store-drain, no overlap.
// This version: NO LDS, NO barrier. Each wave streams its 77-row window
// straight from global (lane c reads x[row*64+c]: identical 256 B coalesced
// wave access as staging had). Halo re-reads hit L1/L2/L3 (input 33.5 MB
// << 256 MB L3) so HBM fetch stays ~input-sized. Waves de-phase freely ->
// memory and VALU overlap statistically across 16 waves/CU.
// All indices compile-time via template recursion (round-3 lesson: anything
// less re-introduces scratch allocas or rematerialized loads).
// ---------------------------------------------------------------------------

template <int T, int R>
struct FmaR {
  static __device__ __forceinline__ void run(const WtArgs& W, const float (&win)[WLEN],
                                             float (&a6)[RPT], float (&a3)[RPT],
                                             float (&a1)[RPT]) {
    a6[R] = fmaf(W.w6[T], win[T + R], a6[R]);
    if constexpr (T >= 15 && T <= 46) a3[R] = fmaf(W.w3[T - 15], win[T + R], a3[R]);
    if constexpr (T >= 25 && T <= 36) a1[R] = fmaf(W.w1[T - 25], win[T + R], a1[R]);
    FmaR<T, R + 1>::run(W, win, a6, a3, a1);
  }
};
template <int T>
struct FmaR<T, RPT> {
  static __device__ __forceinline__ void run(const WtArgs&, const float (&)[WLEN],
                                             float (&)[RPT], float (&)[RPT], float (&)[RPT]) {}
};

// guarded (EDGE) or raw global load of window element K; rowbase is
// wave-uniform -> the EDGE bounds test is a scalar branch, not divergence.
template <int K, bool EDGE>
static __device__ __forceinline__ float ldw(const float* __restrict__ col, int rowbase) {
  if constexpr (EDGE) {
    const int row = rowbase + K;
    return (row >= 0 && row < S_LEN) ? col[K * NCH] : 0.f;
  } else {
    return col[K * NCH];
  }
}

template <int T, bool EDGE>
struct Step {
  static __device__ __forceinline__ void run(const float* __restrict__ col, int rowbase,
                                             const WtArgs& W, float (&win)[WLEN],
                                             float (&a6)[RPT], float (&a3)[RPT],
                                             float (&a1)[RPT]) {
    if constexpr (T + PRE < WLEN) win[T + PRE] = ldw<T + PRE, EDGE>(col, rowbase);
    FmaR<T, 0>::run(W, win, a6, a3, a1);
    Step<T + 1, EDGE>::run(col, rowbase, W, win, a6, a3, a1);
  }
};
template <bool EDGE>
struct Step<62, EDGE> {
  static __device__ __forceinline__ void run(const float* __restrict__, int, const WtArgs&,
                                             float (&)[WLEN], float (&)[RPT],
                                             float (&)[RPT], float (&)[RPT]) {}
};

template <int K, bool EDGE>
struct Pre {
  static __device__ __forceinline__ void run(const float* __restrict__ col, int rowbase,
                                             float (&win)[WLEN]) {
    win[K] = ldw<K, EDGE>(col, rowbase);
    Pre<K + 1, EDGE>::run(col, rowbase, win);
  }
};
template <bool EDGE>
struct Pre<PRE, EDGE> {
  static __device__ __forceinline__ void run(const float* __restrict__, int, float (&)[WLEN]) {}
};

template <int R>
struct Store {
  static __device__ __forceinline__ void run(float* __restrict__ o1, float* __restrict__ o3,
                                             float* __restrict__ o6, const float (&a6)[RPT],
                                             const float (&a3)[RPT], const float (&a1)[RPT]) {
    o1[(size_t)R * NCH] = a1[R];
    o3[(size_t)R * NCH] = a3[R];
    o6[(size_t)R * NCH] = a6[R];
    Store<R + 1>::run(o1, o3, o6, a6, a3, a1);
  }
};
template <>
struct Store<RPT> {
  static __device__ __forceinline__ void run(float* __restrict__, float* __restrict__,
                                             float* __restrict__, const float (&)[RPT],
                                             const float (&)[RPT], const float (&)[RPT]) {}
};

template <int R>
struct Zero {
  static __device__ __forceinline__ void run(float (&a6)[RPT], float (&a3)[RPT], float (&a1)[RPT]) {
    a6[R] = 0.f; a3[R] = 0.f; a1[R] = 0.f;
    Zero<R + 1>::run(a6, a3, a1);
  }
};
template <>
struct Zero<RPT> {
  static __device__ __forceinline__ void run(float (&)[RPT], float (&)[RPT], float (&)[RPT]) {}
};

__global__ __launch_bounds__(256, 4)   // cap 128 VGPR: no spill, 16 waves/CU
void cwt_main(const float* __restrict__ x, float* __restrict__ out, const WtArgs W) {
  const int c     = threadIdx.x;                  // 0..63 (lane = channel)
  const int ty    = threadIdx.y;                  // 0..3 (wave = strip)
  const int b     = blockIdx.y;
  const int strip = blockIdx.x * TY + ty;         // 0..255 within batch
  const int s0w   = strip * RPT;                  // strip's first output row
  const int rowbase = s0w - 31;                   // window row 0 (may be <0)

  const float* col = x + (size_t)b * S_LEN * NCH + (ptrdiff_t)rowbase * NCH + c;

  float win[WLEN];
  float a6[RPT], a3[RPT], a1[RPT];
  Zero<0>::run(a6, a3, a1);

  // strips 0,1 (rowbase<0) and 254,255 (rowbase+76>4095) need zero-padding
  if (strip >= 2 && strip <= 253) {
    Pre<0, false>::run(col, rowbase, win);
    Step<0, false>::run(col, rowbase, W, win, a6, a3, a1);
  } else {
    Pre<0, true>::run(col, rowbase, win);
    Step<0, true>::run(col, rowbase, W, win, a6, a3, a1);
  }

  // stores: 64 lanes x 4 B contiguous per row; planes 0=scale1,1=scale3,2=scale6
  float* o1 = out + (((size_t)b * 3 + 0) * S_LEN + s0w) * NCH + c;
  float* o3 = out + (((size_t)b * 3 + 1) * S_LEN + s0w) * NCH + c;
  float* o6 = out + (((size_t)b * 3 + 2) * S_LEN + s0w) * NCH + c;
  Store<0>::run(o1, o3, o6, a6, a3, a1);
}

// ---------------------------------------------------------------------------
// Host-side weight construction (capture time; kernarg frozen into graph).
// Replicates pywt/gaus1 exactly:
//   x = linspace(-5,5,1024); step = x[1]-x[0];
//   psi = -2x e^{-x^2}/(pi/2)^{1/4}; int_psi = cumsum(psi)*step (serial fp64)
//   j = (arange(10a+1)/(a*step)).astype(int64); f = f32(int_psi[j])
// Fused (conv + diff + trim): w_a[t] = -sqrt(a)*(f[t-1]-f[t]), f[-1]=f[L]=0.
// ---------------------------------------------------------------------------
extern "C" void kernel_launch(void* const* d_in, const int* in_sizes, int n_in,
                              void* d_out, int out_size, void* d_ws, size_t ws_size,
                              hipStream_t stream) {
  (void)n_in; (void)out_size; (void)d_ws; (void)ws_size;
  const float* x = (const float*)d_in[0];
  float* out = (float*)d_out;
  const int B = in_sizes[0] / (S_LEN * NCH);   // 32

  WtArgs W;
  {
    static double ip[1024];
    const double delta = 10.0 / 1023.0;
    const double step  = (-5.0 + delta) + 5.0;       // == numpy x[1]-x[0]
    const double cn    = pow(3.141592653589793 * 0.5, 0.25);
    double s = 0.0;
    for (int i = 0; i < 1024; ++i) {
      const double xi  = (i == 1023) ? 5.0 : ((double)i * delta - 5.0);
      const double psi = (-2.0 * xi) * exp(-(xi * xi)) / cn;
      s += psi;
      ip[i] = s * step;
    }
    const int   as_[3] = {6, 3, 1};
    const int   lf_[3] = {61, 31, 11};               // taps t = 0..lf
    float*      wp_[3] = {W.w6, W.w3, W.w1};
    for (int si = 0; si < 3; ++si) {
      const double denom = (double)as_[si] * step;
      const float  sqa   = (float)sqrt((double)as_[si]);
      const int    lf    = lf_[si];
      for (int t = 0; t <= lf; ++t) {
        float km1 = 0.f, kt = 0.f;
        if (t >= 1)      km1 = (float)ip[(long)(((double)(t - 1)) / denom)];
        if (t <= lf - 1) kt  = (float)ip[(long)(((double)t) / denom)];
        wp_[si][t] = -sqa * (km1 - kt);
      }
    }
  }

  dim3 grid(256 / TY, B);                      // (64, 32) = 2048 blocks
  dim3 block(NCH, TY);                         // 256 threads = 4 waves
  hipLaunchKernelGGL(cwt_main, grid, block, 0, stream, x, out, W);
}